// Round 2
// baseline (3851.608 us; speedup 1.0000x reference)
//
#include <hip/hip_runtime.h>
#include <hip/hip_fp16.h>

// LSTMDecoder: B=32768, LATENT=32, HID=128, NVAR=9, T=60, 2 layers.
// R2: 64 batch rows/block (512 blocks, 2 blocks/CU), W_out folded into G0
// (out-projection off the serial chain), h0 double-buffered -> 3 barriers/step.
// X layout (cols): 0:=1.0 bias | 1:=tflag | 2..15:=0 | 16..143: se
//   144..271: h0 buf0 | 272..399: h0 buf1 | 400..527: h1 (z here during init)

#define TSTEP 60
#define ROWS  64
#define CS    576          // X row stride elems (1152B = 72 16B-units, XOR-swizzle spreads banks)
#define K0    400          // Wp0' stride: [bias16 | se128 | h0 128 | Wfold 128] = 25 tiles
#define K1    272          // Wp1 stride: [h0n 128 | h1 128 | bias16] = 17 tiles
#define KI    176          // Wpi stride: [bias16 | se128 | z32] = 11 tiles
#define KO    144          // Wop stride: [h1 128 | bias16] = 9 tiles
#define NP0   (512*K0)
#define NP1   (512*K1)
#define NPI   (512*KI)
#define NPO   (32*KO)

typedef _Float16 f16x8 __attribute__((ext_vector_type(8)));
typedef float    f32x16 __attribute__((ext_vector_type(16)));

__device__ __forceinline__ float sigm(float x) {
    float e = __builtin_amdgcn_exp2f(x * -1.4426950408889634f);
    return __builtin_amdgcn_rcpf(1.0f + e);
}
__device__ __forceinline__ float tanh_(float x) {
    float e = __builtin_amdgcn_exp2f(x * -2.8853900817779268f);
    return __builtin_amdgcn_rcpf(1.0f + e) * 2.0f - 1.0f;
}

// ---------------- prep: permute + f16-convert + fold weights ----------------
// Wp0'[u'][k], u'=h*4+g (orig row r=g*128+h):
//   k0 = b_ih0+b_hh0 ; k1 = W_ih0[r,:9]@b_out (tflag col) ; k2..15 = 0
//   k16..143  = W_ih0[r, 9:137]   (se)
//   k144..271 = W_hh0[r, :]       (h0)
//   k272..399 = W_ih0[r,:9] @ W_out  (fold, vs h1)
// Wp1[u'][k]: k0..127 = W_ih1 ; k128..255 = W_hh1 ; k256 = b_ih1+b_hh1 ; rest 0
// Wpi[u'][k], u'=h*4+q (q:h0,c0,h1,c1; r=q*128+h):
//   k0 = b_init ; k16..143 = W_init[r,32:160] (se) ; k144..175 = W_init[r,0:32] (z)
// Wop[v][k] (32 rows): v<9: k0..127 = W_out[v,:], k128 = b_out[v]; else 0
__global__ void prep_kernel(const float* __restrict__ Winit, const float* __restrict__ binit,
                            const float* __restrict__ Wih0, const float* __restrict__ Whh0,
                            const float* __restrict__ bih0, const float* __restrict__ bhh0,
                            const float* __restrict__ Wih1, const float* __restrict__ Whh1,
                            const float* __restrict__ bih1, const float* __restrict__ bhh1,
                            const float* __restrict__ Wout, const float* __restrict__ bout,
                            _Float16* __restrict__ ws)
{
    int i = blockIdx.x * 256 + threadIdx.x;
    _Float16* Wp0 = ws;
    _Float16* Wp1 = ws + NP0;
    _Float16* Wpi = ws + NP0 + NP1;
    _Float16* Wop = ws + NP0 + NP1 + NPI;

    if (i < NP0) {
        int u = i / K0, k = i - u * K0;
        int g = u & 3, h = u >> 2, r = g * 128 + h;
        float v = 0.0f;
        if (k == 0)                  v = bih0[r] + bhh0[r];
        else if (k == 1)             { for (int q = 0; q < 9; q++) v += Wih0[r * 137 + q] * bout[q]; }
        else if (k >= 16 && k < 144) v = Wih0[r * 137 + 9 + (k - 16)];
        else if (k >= 144 && k < 272) v = Whh0[r * 128 + (k - 144)];
        else if (k >= 272)           { for (int q = 0; q < 9; q++) v += Wih0[r * 137 + q] * Wout[q * 128 + (k - 272)]; }
        Wp0[i] = (_Float16)v;
    }
    if (i < NP1) {
        int u = i / K1, k = i - u * K1;
        int g = u & 3, h = u >> 2, r = g * 128 + h;
        float v = 0.0f;
        if (k < 128)        v = Wih1[r * 128 + k];
        else if (k < 256)   v = Whh1[r * 128 + (k - 128)];
        else if (k == 256)  v = bih1[r] + bhh1[r];
        Wp1[i] = (_Float16)v;
    }
    if (i < NPI) {
        int u = i / KI, k = i - u * KI;
        int q = u & 3, h = u >> 2, r = q * 128 + h;
        float v = 0.0f;
        if (k == 0)                  v = binit[r];
        else if (k >= 16 && k < 144) v = Winit[r * 160 + 32 + (k - 16)];
        else if (k >= 144)           v = Winit[r * 160 + (k - 144)];
        Wpi[i] = (_Float16)v;
    }
    if (i < NPO) {
        int vv = i / KO, k = i - vv * KO;
        float v = 0.0f;
        if (vv < 9) {
            if (k < 128)       v = Wout[vv * 128 + k];
            else if (k == 128) v = bout[vv];
        }
        Wop[i] = (_Float16)v;
    }
}

// ---------------- main persistent kernel ----------------
__global__ __launch_bounds__(512, 4) void lstm_main(
    const float* __restrict__ z, const int* __restrict__ scen,
    const float* __restrict__ emb, const _Float16* __restrict__ ws,
    float* __restrict__ out)
{
    __shared__ _Float16 Xs[ROWS * CS];

    const int tid = threadIdx.x;
    const int w   = tid >> 6;       // wave 0..7
    const int l   = tid & 63;
    const int hi  = l >> 5;
    const int ln  = l & 31;
    const int hi8 = hi * 8;
    const int Bb  = blockIdx.x * ROWS;

    const _Float16* Wp0 = ws;
    const _Float16* Wp1 = ws + NP0;
    const _Float16* Wpi = ws + NP0 + NP1;
    const _Float16* Wop = ws + NP0 + NP1 + NPI;

    // ct tiles: b = ct*32 + ln. Note key((b+32)) == key(b) -> single xk.
    const int xk  = ((ln >> 1) & 7) << 3;
    const int xb0 = ln * CS;
    const int xb1 = (32 + ln) * CS;

    // ---- zero + fill LDS ----
    for (int i = tid; i < ROWS * CS; i += 512) Xs[i] = (_Float16)0.0f;
    __syncthreads();
    for (int i = tid; i < ROWS * 128; i += 512) {
        int b = i >> 7, j = i & 127;
        int sc  = scen[Bb + b];
        int key = ((b >> 1) & 7) << 3;
        Xs[b * CS + ((16 + j) ^ key)] = (_Float16)emb[sc * 128 + j];
    }
    for (int i = tid; i < ROWS * 32; i += 512) {
        int b = i >> 5, j = i & 31;
        int key = ((b >> 1) & 7) << 3;
        Xs[b * CS + ((400 + j) ^ key)] = (_Float16)z[(Bb + b) * 32 + j];
    }
    if (tid < ROWS) {
        int key = ((tid >> 1) & 7) << 3;
        Xs[tid * CS + (0 ^ key)] = (_Float16)1.0f;   // col0 bias; col1 (tflag) stays 0
    }
    __syncthreads();

    float c0r[2][4][2], c1r[2][4][2];   // [rt][rg][ct]

    // ---- init GEMM: rows u'=h*4+q over [bias|se|z] ----
    {
        const int r0 = (w * 64 + ln) * KI + hi8;
        const int r1 = r0 + 32 * KI;
        f32x16 acc[2][2] = {};
        for (int kt = 0; kt < 11; kt++) {
            f16x8 a0 = *(const f16x8*)(Wpi + r0 + kt * 16);
            f16x8 a1 = *(const f16x8*)(Wpi + r1 + kt * 16);
            int xc = (kt < 9 ? kt * 16 : 400 + (kt - 9) * 16) + hi8;
            f16x8 b0 = *(const f16x8*)(Xs + xb0 + (xc ^ xk));
            f16x8 b1 = *(const f16x8*)(Xs + xb1 + (xc ^ xk));
            acc[0][0] = __builtin_amdgcn_mfma_f32_32x32x16_f16(a0, b0, acc[0][0], 0, 0, 0);
            acc[0][1] = __builtin_amdgcn_mfma_f32_32x32x16_f16(a0, b1, acc[0][1], 0, 0, 0);
            acc[1][0] = __builtin_amdgcn_mfma_f32_32x32x16_f16(a1, b0, acc[1][0], 0, 0, 0);
            acc[1][1] = __builtin_amdgcn_mfma_f32_32x32x16_f16(a1, b1, acc[1][1], 0, 0, 0);
        }
        __syncthreads();   // z reads done before h1 overwrite
#pragma unroll
        for (int rt = 0; rt < 2; rt++)
#pragma unroll
        for (int ct = 0; ct < 2; ct++) {
            int xb = ct ? xb1 : xb0;
#pragma unroll
            for (int rg = 0; rg < 4; rg++) {
                int hid = (w << 4) + rt * 8 + 2 * rg + hi;
                c0r[rt][rg][ct] = acc[rt][ct][4 * rg + 1];
                c1r[rt][rg][ct] = acc[rt][ct][4 * rg + 3];
                Xs[xb + ((144 + hid) ^ xk)] = (_Float16)acc[rt][ct][4 * rg + 0];
                Xs[xb + ((400 + hid) ^ xk)] = (_Float16)acc[rt][ct][4 * rg + 2];
            }
        }
    }
    __syncthreads();

    // ---- time loop ----
#pragma unroll 1
    for (int t = 0; t < TSTEP; t++) {
        const int p = t & 1;

        // ===== G0: gates0 = Wp0' @ [bias|se|h0[p]|h1]^T =====
        f32x16 acc[2][2] = {};
        {
            const int nk = (t == 0) ? 17 : 25;
            const int r0 = (w * 64 + ln) * K0 + hi8;
            const int r1 = r0 + 32 * K0;
            f16x8 a0 = *(const f16x8*)(Wp0 + r0);
            f16x8 a1 = *(const f16x8*)(Wp0 + r1);
#pragma unroll 1
            for (int kt = 0; kt < nk; kt++) {
                f16x8 ca = a0, cb = a1;
                if (kt + 1 < nk) {
                    a0 = *(const f16x8*)(Wp0 + r0 + (kt + 1) * 16);
                    a1 = *(const f16x8*)(Wp0 + r1 + (kt + 1) * 16);
                }
                int xc = kt * 16 + hi8 + (kt >= 17 ? 128 : (kt >= 9 ? (p << 7) : 0));
                f16x8 b0 = *(const f16x8*)(Xs + xb0 + (xc ^ xk));
                f16x8 b1 = *(const f16x8*)(Xs + xb1 + (xc ^ xk));
                acc[0][0] = __builtin_amdgcn_mfma_f32_32x32x16_f16(ca, b0, acc[0][0], 0, 0, 0);
                acc[0][1] = __builtin_amdgcn_mfma_f32_32x32x16_f16(ca, b1, acc[0][1], 0, 0, 0);
                acc[1][0] = __builtin_amdgcn_mfma_f32_32x32x16_f16(cb, b0, acc[1][0], 0, 0, 0);
                acc[1][1] = __builtin_amdgcn_mfma_f32_32x32x16_f16(cb, b1, acc[1][1], 0, 0, 0);
            }
        }

        // ===== E0 (no barrier before: writes go to h0[1-p], untouched this phase) =====
        const int hb0 = 144 + (1 - p) * 128;
#pragma unroll
        for (int rt = 0; rt < 2; rt++)
#pragma unroll
        for (int ct = 0; ct < 2; ct++) {
            int xb = ct ? xb1 : xb0;
#pragma unroll
            for (int rg = 0; rg < 4; rg++) {
                float gi = acc[rt][ct][4 * rg + 0];
                float gf = acc[rt][ct][4 * rg + 1];
                float gg = acc[rt][ct][4 * rg + 2];
                float go = acc[rt][ct][4 * rg + 3];
                float c = sigm(gf) * c0r[rt][rg][ct] + sigm(gi) * tanh_(gg);
                c0r[rt][rg][ct] = c;
                float h = sigm(go) * tanh_(c);
                int hid = (w << 4) + rt * 8 + 2 * rg + hi;
                Xs[xb + ((hb0 + hid) ^ xk)] = (_Float16)h;
            }
        }
        __syncthreads();   // barrier A: h0n visible

        if (t == 0 && tid < ROWS) {   // enable tflag (bfold) for t>=1; G1 weights at col1 are 0
            int key = ((tid >> 1) & 7) << 3;
            Xs[tid * CS + (1 ^ key)] = (_Float16)1.0f;
        }

        // ===== G1: gates1 = Wp1 @ [h0n|h1|bias]^T =====
#pragma unroll
        for (int rt = 0; rt < 2; rt++)
#pragma unroll
        for (int ct = 0; ct < 2; ct++) acc[rt][ct] = (f32x16){};
        {
            const int r0 = (w * 64 + ln) * K1 + hi8;
            const int r1 = r0 + 32 * K1;
            f16x8 a0 = *(const f16x8*)(Wp1 + r0);
            f16x8 a1 = *(const f16x8*)(Wp1 + r1);
#pragma unroll 1
            for (int kt = 0; kt < 17; kt++) {
                f16x8 ca = a0, cb = a1;
                if (kt < 16) {
                    a0 = *(const f16x8*)(Wp1 + r0 + (kt + 1) * 16);
                    a1 = *(const f16x8*)(Wp1 + r1 + (kt + 1) * 16);
                }
                int xc = (kt < 8 ? hb0 + kt * 16 : (kt < 16 ? 400 + (kt - 8) * 16 : 0)) + hi8;
                f16x8 b0 = *(const f16x8*)(Xs + xb0 + (xc ^ xk));
                f16x8 b1 = *(const f16x8*)(Xs + xb1 + (xc ^ xk));
                acc[0][0] = __builtin_amdgcn_mfma_f32_32x32x16_f16(ca, b0, acc[0][0], 0, 0, 0);
                acc[0][1] = __builtin_amdgcn_mfma_f32_32x32x16_f16(ca, b1, acc[0][1], 0, 0, 0);
                acc[1][0] = __builtin_amdgcn_mfma_f32_32x32x16_f16(cb, b0, acc[1][0], 0, 0, 0);
                acc[1][1] = __builtin_amdgcn_mfma_f32_32x32x16_f16(cb, b1, acc[1][1], 0, 0, 0);
            }
        }
        __syncthreads();   // barrier B: G1 reads done before h1 in-place overwrite

        // ===== E1: write h1n in place =====
#pragma unroll
        for (int rt = 0; rt < 2; rt++)
#pragma unroll
        for (int ct = 0; ct < 2; ct++) {
            int xb = ct ? xb1 : xb0;
#pragma unroll
            for (int rg = 0; rg < 4; rg++) {
                float gi = acc[rt][ct][4 * rg + 0];
                float gf = acc[rt][ct][4 * rg + 1];
                float gg = acc[rt][ct][4 * rg + 2];
                float go = acc[rt][ct][4 * rg + 3];
                float c = sigm(gf) * c1r[rt][rg][ct] + sigm(gi) * tanh_(gg);
                c1r[rt][rg][ct] = c;
                float h = sigm(go) * tanh_(c);
                int hid = (w << 4) + rt * 8 + 2 * rg + hi;
                Xs[xb + ((400 + hid) ^ xk)] = (_Float16)h;
            }
        }
        __syncthreads();   // barrier C: h1n visible (for out-proj AND next G0's fold)

        // ===== out-proj (waves 0,1) — off the serial chain, no trailing barrier =====
        if (w < 2) {
            const int xb = w ? xb1 : xb0;
            const int rr = ln * KO + hi8;
            f32x16 aC = {};
#pragma unroll
            for (int kt = 0; kt < 9; kt++) {
                f16x8 av = *(const f16x8*)(Wop + rr + kt * 16);
                int xc = (kt < 8 ? 400 + kt * 16 : 0) + hi8;
                f16x8 bv = *(const f16x8*)(Xs + xb + (xc ^ xk));
                aC = __builtin_amdgcn_mfma_f32_32x32x16_f16(av, bv, aC, 0, 0, 0);
            }
            float* op = out + ((size_t)(Bb + w * 32 + ln) * TSTEP + t) * 9;
            if (hi == 0) {
                op[0] = aC[0]; op[1] = aC[1]; op[2] = aC[2]; op[3] = aC[3]; op[8] = aC[4];
            } else {
                op[4] = aC[0]; op[5] = aC[1]; op[6] = aC[2]; op[7] = aC[3];
            }
        }
    }
}

extern "C" void kernel_launch(void* const* d_in, const int* in_sizes, int n_in,
                              void* d_out, int out_size, void* d_ws, size_t ws_size,
                              hipStream_t stream) {
    const float* z     = (const float*)d_in[0];
    const int*   scen  = (const int*)d_in[1];
    // d_in[2] = seq_length (fixed 60)
    const float* emb   = (const float*)d_in[3];
    const float* Winit = (const float*)d_in[4];
    const float* binit = (const float*)d_in[5];
    const float* Wih0  = (const float*)d_in[6];
    const float* Whh0  = (const float*)d_in[7];
    const float* bih0  = (const float*)d_in[8];
    const float* bhh0  = (const float*)d_in[9];
    const float* Wih1  = (const float*)d_in[10];
    const float* Whh1  = (const float*)d_in[11];
    const float* bih1  = (const float*)d_in[12];
    const float* bhh1  = (const float*)d_in[13];
    const float* Wout  = (const float*)d_in[14];
    const float* bout  = (const float*)d_in[15];
    _Float16* ws  = (_Float16*)d_ws;
    float*    out = (float*)d_out;

    prep_kernel<<<(NP0 + 255) / 256, 256, 0, stream>>>(
        Winit, binit, Wih0, Whh0, bih0, bhh0, Wih1, Whh1, bih1, bhh1, Wout, bout, ws);
    lstm_main<<<512, 512, 0, stream>>>(z, scen, emb, ws, out);
}

// Round 3
// 2998.342 us; speedup vs baseline: 1.2846x; 1.2846x over previous
//
#include <hip/hip_runtime.h>
#include <hip/hip_fp16.h>

// LSTMDecoder: B=32768, LATENT=32, HID=128, NVAR=9, T=60, 2 layers.
// R3: kt-major (coalesced) weight layout [kt][512][16]; LDS out-staging with
// chunked coalesced flush. 64 batch rows/block, 512 blocks (2/CU), W_out folded
// into G0, h0 double-buffered, 3 barriers/step.
// X cols: 0 bias | 1 tflag | 2..15 zero | 16..143 se | 144..399 h0 dbuf | 400..527 h1 (z at init)

#define TSTEP 60
#define ROWS  64
#define CS    576
#define NKT0  25           // G0 k-tiles: [bias16|se128|h0 128|fold128]
#define NKT1  17           // G1 k-tiles: [h0n128|h1 128|bias16]
#define NKTI  11           // init k-tiles: [bias16|se128|z32]
#define NKTO  9            // out k-tiles: [h1 128|bias16]
#define KTSZ  8192         // 512 rows * 16 elems per k-tile
#define NP0   (NKT0*KTSZ)
#define NP1   (NKT1*KTSZ)
#define NPI   (NKTI*KTSZ)
#define NPO   (NKTO*512)   // 32 rows * 16

typedef _Float16 f16x8 __attribute__((ext_vector_type(8)));
typedef float    f32x16 __attribute__((ext_vector_type(16)));

__device__ __forceinline__ float sigm(float x) {
    float e = __builtin_amdgcn_exp2f(x * -1.4426950408889634f);
    return __builtin_amdgcn_rcpf(1.0f + e);
}
__device__ __forceinline__ float tanh_(float x) {
    float e = __builtin_amdgcn_exp2f(x * -2.8853900817779268f);
    return __builtin_amdgcn_rcpf(1.0f + e) * 2.0f - 1.0f;
}

// ---------------- prep: permute + f16-convert + fold, kt-major ----------------
// k-logic per array (k = kt*16 + e, u' = h*4+g, r = g*128+h):
// Wp0: k0=b_ih0+b_hh0 ; k1=W_ih0[r,:9]@b_out ; k16..143=W_ih0[r,9:137] ;
//      k144..271=W_hh0[r,:] ; k272..399=W_ih0[r,:9]@W_out
// Wp1: k0..127=W_ih1 ; k128..255=W_hh1 ; k256=b_ih1+b_hh1
// Wpi (u'=h*4+q, r=q*128+h): k0=b_init ; k16..143=W_init[r,32:160] ; k144..175=W_init[r,0:32]
// Wop (32 rows): v<9: k0..127=W_out[v,:], k128=b_out[v]
__global__ void prep_kernel(const float* __restrict__ Winit, const float* __restrict__ binit,
                            const float* __restrict__ Wih0, const float* __restrict__ Whh0,
                            const float* __restrict__ bih0, const float* __restrict__ bhh0,
                            const float* __restrict__ Wih1, const float* __restrict__ Whh1,
                            const float* __restrict__ bih1, const float* __restrict__ bhh1,
                            const float* __restrict__ Wout, const float* __restrict__ bout,
                            _Float16* __restrict__ ws)
{
    int i = blockIdx.x * 256 + threadIdx.x;
    _Float16* Wp0 = ws;
    _Float16* Wp1 = ws + NP0;
    _Float16* Wpi = ws + NP0 + NP1;
    _Float16* Wop = ws + NP0 + NP1 + NPI;

    if (i < NP0) {
        int kt = i >> 13, rem = i & 8191, u = rem >> 4, e = rem & 15;
        int k = kt * 16 + e;
        int g = u & 3, h = u >> 2, r = g * 128 + h;
        float v = 0.0f;
        if (k == 0)                   v = bih0[r] + bhh0[r];
        else if (k == 1)              { for (int q = 0; q < 9; q++) v += Wih0[r * 137 + q] * bout[q]; }
        else if (k >= 16 && k < 144)  v = Wih0[r * 137 + 9 + (k - 16)];
        else if (k >= 144 && k < 272) v = Whh0[r * 128 + (k - 144)];
        else if (k >= 272)            { for (int q = 0; q < 9; q++) v += Wih0[r * 137 + q] * Wout[q * 128 + (k - 272)]; }
        Wp0[i] = (_Float16)v;
    }
    if (i < NP1) {
        int kt = i >> 13, rem = i & 8191, u = rem >> 4, e = rem & 15;
        int k = kt * 16 + e;
        int g = u & 3, h = u >> 2, r = g * 128 + h;
        float v = 0.0f;
        if (k < 128)        v = Wih1[r * 128 + k];
        else if (k < 256)   v = Whh1[r * 128 + (k - 128)];
        else if (k == 256)  v = bih1[r] + bhh1[r];
        Wp1[i] = (_Float16)v;
    }
    if (i < NPI) {
        int kt = i >> 13, rem = i & 8191, u = rem >> 4, e = rem & 15;
        int k = kt * 16 + e;
        int q = u & 3, h = u >> 2, r = q * 128 + h;
        float v = 0.0f;
        if (k == 0)                   v = binit[r];
        else if (k >= 16 && k < 144)  v = Winit[r * 160 + 32 + (k - 16)];
        else if (k >= 144 && k < 176) v = Winit[r * 160 + (k - 144)];
        Wpi[i] = (_Float16)v;
    }
    if (i < NPO) {
        int kt = i >> 9, rem = i & 511, vv = rem >> 4, e = rem & 15;
        int k = kt * 16 + e;
        float v = 0.0f;
        if (vv < 9) {
            if (k < 128)       v = Wout[vv * 128 + k];
            else if (k == 128) v = bout[vv];
        }
        Wop[i] = (_Float16)v;
    }
}

// ---------------- main persistent kernel ----------------
__global__ __launch_bounds__(512, 4) void lstm_main(
    const float* __restrict__ z, const int* __restrict__ scen,
    const float* __restrict__ emb, const _Float16* __restrict__ ws,
    float* __restrict__ out)
{
    __shared__ _Float16 Xs[ROWS * CS];
    __shared__ _Float16 Os[ROWS * 63];     // out staging: [row][tc*9+v], tc = t%7

    const int tid = threadIdx.x;
    const int w   = tid >> 6;
    const int l   = tid & 63;
    const int hi  = l >> 5;
    const int ln  = l & 31;
    const int hi8 = hi * 8;
    const int Bb  = blockIdx.x * ROWS;

    const _Float16* Wp0 = ws;
    const _Float16* Wp1 = ws + NP0;
    const _Float16* Wpi = ws + NP0 + NP1;
    const _Float16* Wop = ws + NP0 + NP1 + NPI;

    const int xk  = ((ln >> 1) & 7) << 3;
    const int xb0 = ln * CS;
    const int xb1 = (32 + ln) * CS;
    const int rwa = (w * 64 + ln) * 16 + hi8;   // coalesced A-frag base within a k-tile

    // ---- zero + fill LDS ----
    for (int i = tid; i < ROWS * CS; i += 512) Xs[i] = (_Float16)0.0f;
    __syncthreads();
    for (int i = tid; i < ROWS * 128; i += 512) {
        int b = i >> 7, j = i & 127;
        int sc  = scen[Bb + b];
        int key = ((b >> 1) & 7) << 3;
        Xs[b * CS + ((16 + j) ^ key)] = (_Float16)emb[sc * 128 + j];
    }
    for (int i = tid; i < ROWS * 32; i += 512) {
        int b = i >> 5, j = i & 31;
        int key = ((b >> 1) & 7) << 3;
        Xs[b * CS + ((400 + j) ^ key)] = (_Float16)z[(Bb + b) * 32 + j];
    }
    if (tid < ROWS) {
        int key = ((tid >> 1) & 7) << 3;
        Xs[tid * CS + (0 ^ key)] = (_Float16)1.0f;   // bias col; tflag (col1) stays 0 until t>=1
    }
    __syncthreads();

    float c0r[2][4][2], c1r[2][4][2];

    // ---- init GEMM ----
    {
        f32x16 acc[2][2] = {};
        const _Float16* p = Wpi + rwa;
        f16x8 a0 = *(const f16x8*)(p);
        f16x8 a1 = *(const f16x8*)(p + 512);
#pragma unroll 1
        for (int kt = 0; kt < NKTI; kt++) {
            f16x8 ca = a0, cb = a1;
            if (kt + 1 < NKTI) {
                a0 = *(const f16x8*)(p + (kt + 1) * KTSZ);
                a1 = *(const f16x8*)(p + (kt + 1) * KTSZ + 512);
            }
            int xc = (kt < 9 ? kt * 16 : 400 + (kt - 9) * 16) + hi8;
            f16x8 b0 = *(const f16x8*)(Xs + xb0 + (xc ^ xk));
            f16x8 b1 = *(const f16x8*)(Xs + xb1 + (xc ^ xk));
            acc[0][0] = __builtin_amdgcn_mfma_f32_32x32x16_f16(ca, b0, acc[0][0], 0, 0, 0);
            acc[0][1] = __builtin_amdgcn_mfma_f32_32x32x16_f16(ca, b1, acc[0][1], 0, 0, 0);
            acc[1][0] = __builtin_amdgcn_mfma_f32_32x32x16_f16(cb, b0, acc[1][0], 0, 0, 0);
            acc[1][1] = __builtin_amdgcn_mfma_f32_32x32x16_f16(cb, b1, acc[1][1], 0, 0, 0);
        }
        __syncthreads();   // z reads done before h1 overwrite
#pragma unroll
        for (int rt = 0; rt < 2; rt++)
#pragma unroll
        for (int ct = 0; ct < 2; ct++) {
            int xb = ct ? xb1 : xb0;
#pragma unroll
            for (int rg = 0; rg < 4; rg++) {
                int hid = (w << 4) + rt * 8 + 2 * rg + hi;
                c0r[rt][rg][ct] = acc[rt][ct][4 * rg + 1];
                c1r[rt][rg][ct] = acc[rt][ct][4 * rg + 3];
                Xs[xb + ((144 + hid) ^ xk)] = (_Float16)acc[rt][ct][4 * rg + 0];
                Xs[xb + ((400 + hid) ^ xk)] = (_Float16)acc[rt][ct][4 * rg + 2];
            }
        }
    }
    __syncthreads();

    // ---- time loop ----
#pragma unroll 1
    for (int t = 0; t < TSTEP; t++) {
        const int p = t & 1;

        // ===== G0 =====
        f32x16 acc[2][2] = {};
        {
            const int nk = (t == 0) ? 17 : NKT0;
            const _Float16* pw = Wp0 + rwa;
            f16x8 a0 = *(const f16x8*)(pw);
            f16x8 a1 = *(const f16x8*)(pw + 512);
#pragma unroll 1
            for (int kt = 0; kt < nk; kt++) {
                f16x8 ca = a0, cb = a1;
                if (kt + 1 < nk) {
                    a0 = *(const f16x8*)(pw + (kt + 1) * KTSZ);
                    a1 = *(const f16x8*)(pw + (kt + 1) * KTSZ + 512);
                }
                int xc = kt * 16 + hi8 + (kt >= 17 ? 128 : (kt >= 9 ? (p << 7) : 0));
                f16x8 b0 = *(const f16x8*)(Xs + xb0 + (xc ^ xk));
                f16x8 b1 = *(const f16x8*)(Xs + xb1 + (xc ^ xk));
                acc[0][0] = __builtin_amdgcn_mfma_f32_32x32x16_f16(ca, b0, acc[0][0], 0, 0, 0);
                acc[0][1] = __builtin_amdgcn_mfma_f32_32x32x16_f16(ca, b1, acc[0][1], 0, 0, 0);
                acc[1][0] = __builtin_amdgcn_mfma_f32_32x32x16_f16(cb, b0, acc[1][0], 0, 0, 0);
                acc[1][1] = __builtin_amdgcn_mfma_f32_32x32x16_f16(cb, b1, acc[1][1], 0, 0, 0);
            }
        }

        // ===== E0: writes h0[1-p] (not read this phase) =====
        const int hb0 = 144 + (1 - p) * 128;
#pragma unroll
        for (int rt = 0; rt < 2; rt++)
#pragma unroll
        for (int ct = 0; ct < 2; ct++) {
            int xb = ct ? xb1 : xb0;
#pragma unroll
            for (int rg = 0; rg < 4; rg++) {
                float gi = acc[rt][ct][4 * rg + 0];
                float gf = acc[rt][ct][4 * rg + 1];
                float gg = acc[rt][ct][4 * rg + 2];
                float go = acc[rt][ct][4 * rg + 3];
                float c = sigm(gf) * c0r[rt][rg][ct] + sigm(gi) * tanh_(gg);
                c0r[rt][rg][ct] = c;
                float h = sigm(go) * tanh_(c);
                int hid = (w << 4) + rt * 8 + 2 * rg + hi;
                Xs[xb + ((hb0 + hid) ^ xk)] = (_Float16)h;
            }
        }
        __syncthreads();   // barrier A: h0n visible

        if (t == 0 && tid < ROWS) {   // enable fold-bias col for t>=1
            int key = ((tid >> 1) & 7) << 3;
            Xs[tid * CS + (1 ^ key)] = (_Float16)1.0f;
        }

        // ===== G1 =====
#pragma unroll
        for (int rt = 0; rt < 2; rt++)
#pragma unroll
        for (int ct = 0; ct < 2; ct++) acc[rt][ct] = (f32x16){};
        {
            const _Float16* pw = Wp1 + rwa;
            f16x8 a0 = *(const f16x8*)(pw);
            f16x8 a1 = *(const f16x8*)(pw + 512);
#pragma unroll 1
            for (int kt = 0; kt < NKT1; kt++) {
                f16x8 ca = a0, cb = a1;
                if (kt + 1 < NKT1) {
                    a0 = *(const f16x8*)(pw + (kt + 1) * KTSZ);
                    a1 = *(const f16x8*)(pw + (kt + 1) * KTSZ + 512);
                }
                int xc = (kt < 8 ? hb0 + kt * 16 : (kt < 16 ? 400 + (kt - 8) * 16 : 0)) + hi8;
                f16x8 b0 = *(const f16x8*)(Xs + xb0 + (xc ^ xk));
                f16x8 b1 = *(const f16x8*)(Xs + xb1 + (xc ^ xk));
                acc[0][0] = __builtin_amdgcn_mfma_f32_32x32x16_f16(ca, b0, acc[0][0], 0, 0, 0);
                acc[0][1] = __builtin_amdgcn_mfma_f32_32x32x16_f16(ca, b1, acc[0][1], 0, 0, 0);
                acc[1][0] = __builtin_amdgcn_mfma_f32_32x32x16_f16(cb, b0, acc[1][0], 0, 0, 0);
                acc[1][1] = __builtin_amdgcn_mfma_f32_32x32x16_f16(cb, b1, acc[1][1], 0, 0, 0);
            }
        }
        __syncthreads();   // barrier B: G1 reads done before h1 overwrite

        // ===== E1: write h1n in place =====
#pragma unroll
        for (int rt = 0; rt < 2; rt++)
#pragma unroll
        for (int ct = 0; ct < 2; ct++) {
            int xb = ct ? xb1 : xb0;
#pragma unroll
            for (int rg = 0; rg < 4; rg++) {
                float gi = acc[rt][ct][4 * rg + 0];
                float gf = acc[rt][ct][4 * rg + 1];
                float gg = acc[rt][ct][4 * rg + 2];
                float go = acc[rt][ct][4 * rg + 3];
                float c = sigm(gf) * c1r[rt][rg][ct] + sigm(gi) * tanh_(gg);
                c1r[rt][rg][ct] = c;
                float h = sigm(go) * tanh_(c);
                int hid = (w << 4) + rt * 8 + 2 * rg + hi;
                Xs[xb + ((400 + hid) ^ xk)] = (_Float16)h;
            }
        }
        __syncthreads();   // barrier C: h1n visible

        // ===== out-proj (waves 0,1) -> Os staging =====
        const int tc = t % 7;
        if (w < 2) {
            const int xb = w ? xb1 : xb0;
            f32x16 aC = {};
#pragma unroll
            for (int kt = 0; kt < NKTO; kt++) {
                f16x8 av = *(const f16x8*)(Wop + kt * 512 + ln * 16 + hi8);
                int xc = (kt < 8 ? 400 + kt * 16 : 0) + hi8;
                f16x8 bv = *(const f16x8*)(Xs + xb + (xc ^ xk));
                aC = __builtin_amdgcn_mfma_f32_32x32x16_f16(av, bv, aC, 0, 0, 0);
            }
            _Float16* os = Os + (w * 32 + ln) * 63 + tc * 9;
            if (hi == 0) {
                os[0] = (_Float16)aC[0]; os[1] = (_Float16)aC[1];
                os[2] = (_Float16)aC[2]; os[3] = (_Float16)aC[3];
                os[8] = (_Float16)aC[4];
            } else {
                os[4] = (_Float16)aC[0]; os[5] = (_Float16)aC[1];
                os[6] = (_Float16)aC[2]; os[7] = (_Float16)aC[3];
            }
        }

        // ===== chunked coalesced flush =====
        if (tc == 6 || t == TSTEP - 1) {
            __syncthreads();           // out-proj writes visible
            const int t0 = t - tc;
            const int ns = tc + 1;
            const int run = ns * 9;
            const int tot = ROWS * run;
            for (int q = tid; q < tot; q += 512) {
                int row = q / run, j = q - row * run;
                out[(size_t)(Bb + row) * (TSTEP * 9) + t0 * 9 + j] = (float)Os[row * 63 + j];
            }
        }
    }
}

extern "C" void kernel_launch(void* const* d_in, const int* in_sizes, int n_in,
                              void* d_out, int out_size, void* d_ws, size_t ws_size,
                              hipStream_t stream) {
    const float* z     = (const float*)d_in[0];
    const int*   scen  = (const int*)d_in[1];
    // d_in[2] = seq_length (fixed 60)
    const float* emb   = (const float*)d_in[3];
    const float* Winit = (const float*)d_in[4];
    const float* binit = (const float*)d_in[5];
    const float* Wih0  = (const float*)d_in[6];
    const float* Whh0  = (const float*)d_in[7];
    const float* bih0  = (const float*)d_in[8];
    const float* bhh0  = (const float*)d_in[9];
    const float* Wih1  = (const float*)d_in[10];
    const float* Whh1  = (const float*)d_in[11];
    const float* bih1  = (const float*)d_in[12];
    const float* bhh1  = (const float*)d_in[13];
    const float* Wout  = (const float*)d_in[14];
    const float* bout  = (const float*)d_in[15];
    _Float16* ws  = (_Float16*)d_ws;
    float*    out = (float*)d_out;

    prep_kernel<<<(NP0 + 255) / 256, 256, 0, stream>>>(
        Winit, binit, Wih0, Whh0, bih0, bhh0, Wih1, Whh1, bih1, bhh1, Wout, bout, ws);
    lstm_main<<<512, 512, 0, stream>>>(z, scen, emb, ws, out);
}